// Round 5
// baseline (830.787 us; speedup 1.0000x reference)
//
#include <hip/hip_runtime.h>
#include <hip/hip_bf16.h>
#include <cmath>

#define NN 20000   // nodes
#define NE 60000   // edges
#define NS 3000    // subgraphs
#define NG 128     // graphs
#define HIDN 128   // hidden dim of edge-attr MLP

typedef float f32x16 __attribute__((ext_vector_type(16)));
typedef __bf16 bf16x8 __attribute__((ext_vector_type(8)));

__device__ __forceinline__ float eluf(float v) { return v > 0.f ? v : expm1f(v); }

__device__ __forceinline__ unsigned int packbf(float lo, float hi) {
    unsigned short l = __builtin_bit_cast(unsigned short, (__bf16)lo);
    unsigned short h = __builtin_bit_cast(unsigned short, (__bf16)hi);
    return ((unsigned int)h << 16) | l;
}

template <int CH>
struct alignas((CH * 2 < 16) ? (CH * 2) : 16) HPack { __bf16 v[CH]; };

// async global->LDS, 16B per lane; lds ptr must be wave-uniform (HW writes base + lane*16)
__device__ __forceinline__ void gload_lds16(const void* g, void* l) {
    __builtin_amdgcn_global_load_lds(
        (const __attribute__((address_space(1))) unsigned int*)g,
        (__attribute__((address_space(3))) unsigned int*)l, 16, 0, 0);
}

// ---------------- h = relu(ea @ w1 + b1)  (E x 128, bf16) ----------------
__global__ void k_h(const float* __restrict__ ea, const float* __restrict__ w1,
                    const float* __restrict__ b1, __bf16* __restrict__ hb) {
    int idx = blockIdx.x * 256 + threadIdx.x;
    if (idx >= NE * HIDN) return;
    int e = idx >> 7, j = idx & 127;
    float s = b1[j];
#pragma unroll
    for (int d = 0; d < 5; ++d) s = fmaf(ea[e * 5 + d], w1[d * HIDN + j], s);
    hb[idx] = (__bf16)fmaxf(s, 0.f);
}

// ---------------- w2t[o][kg] = bf16( kg<128*MI ? w2[kg*MO+o] : b2[(kg-128MI)*MO+o] ) ----------------
template <int MI, int MO>
__global__ void k_w2t(const float* __restrict__ w2, const float* __restrict__ b2,
                      __bf16* __restrict__ w2t) {
    constexpr int KP = 129 * MI;
    constexpr int KF = 128 * MI;
    int idx = blockIdx.x * 256 + threadIdx.x;
    if (idx >= MO * KP) return;
    int o = idx / KP, kg = idx % KP;
    float v = (kg < KF) ? w2[(size_t)kg * MO + o] : b2[(kg - KF) * MO + o];
    w2t[idx] = (__bf16)v;
}

// ---------------- out = xi @ root + bias  (initializes the agg buffer) ----------------
template <int MI, int MO, int XS>
__global__ void k_root(const float* __restrict__ xi, const float* __restrict__ root,
                       const float* __restrict__ bias, float* __restrict__ out) {
    int idx = blockIdx.x * 256 + threadIdx.x;
    if (idx >= NN * MO) return;
    int n = idx / MO, o = idx % MO;
    float s = bias[o];
#pragma unroll
    for (int i = 0; i < MI; ++i) s = fmaf(xi[(size_t)n * XS + i], root[i * MO + o], s);
    out[idx] = s;
}

// ---------------- MFMA edge kernel, LDS-staged B ----------------
// GEMM: msg[e,o] = sum_kg G[e,kg]*w2t[o][kg],  G[e, k*MI+i] = hfac(e,k)*xi[src[e],i]
// B staged in LDS via global_load_lds (double-buffered CH-k chunks), shared by all 4 waves.
// Wave = 64 edges (2 M-tiles of 32) x full MO. K split across blockIdx.y.
// x fragments resident as PACKED bf16 (VGPR budget for 4 waves/SIMD).
template <int MI, int MO, int XS, int KSPLIT, int CH>
__global__ __launch_bounds__(256, 4) void k_edge_mfma(
    const float* __restrict__ xi, const __bf16* __restrict__ hb,
    const __bf16* __restrict__ w2t,
    const int* __restrict__ src, const int* __restrict__ dst,
    float* __restrict__ out) {
    constexpr int PH  = MI / 16;        // K-steps per k value
    constexpr int KP  = 129 * MI;       // w2t row length
    constexpr int NT  = MO / 32;        // N tiles
    constexpr int KCH = 128 / KSPLIT;   // k values per y-block (main loop)
    constexpr int NCH = KCH / CH;       // chunks per y-block
    constexpr int ITEMS = CH * PH * NT; // 1KB items per chunk
    static_assert(ITEMS == 16, "keep LDS at 2x16KB");

    __shared__ __align__(16) __bf16 sb[2][ITEMS * 512];

    const int lane = threadIdx.x & 63;
    const int w    = threadIdx.x >> 6;
    const int lo5  = lane & 31;
    const int hi   = lane >> 5;
    const int e0   = blockIdx.x * 256 + w * 64;   // may exceed NE for tail waves: no early return (barriers)

    const int kb = KCH * (int)blockIdx.y;

    int r0 = e0 + lo5, r1 = e0 + 32 + lo5;
    const int rc0 = (r0 < NE) ? r0 : 0;
    const int rc1 = (r1 < NE) ? r1 : 0;
    const int s0 = src[rc0];
    const int s1 = src[rc1];

    // gather this lane's x fragment subset into registers, packed bf16 (2 per uint)
    unsigned int xp0[PH][4], xp1[PH][4];
    {
        const float* xb0 = xi + (size_t)s0 * XS + hi * 8;
        const float* xb1 = xi + (size_t)s1 * XS + hi * 8;
#pragma unroll
        for (int p = 0; p < PH; ++p) {
            float4 a = *reinterpret_cast<const float4*>(xb0 + p * 16);
            float4 b = *reinterpret_cast<const float4*>(xb0 + p * 16 + 4);
            xp0[p][0] = packbf(a.x, a.y); xp0[p][1] = packbf(a.z, a.w);
            xp0[p][2] = packbf(b.x, b.y); xp0[p][3] = packbf(b.z, b.w);
            float4 c = *reinterpret_cast<const float4*>(xb1 + p * 16);
            float4 d = *reinterpret_cast<const float4*>(xb1 + p * 16 + 4);
            xp1[p][0] = packbf(c.x, c.y); xp1[p][1] = packbf(c.z, c.w);
            xp1[p][2] = packbf(d.x, d.y); xp1[p][3] = packbf(d.z, d.w);
        }
    }

    f32x16 acc[2][NT];
#pragma unroll
    for (int m = 0; m < 2; ++m)
#pragma unroll
        for (int n = 0; n < NT; ++n)
#pragma unroll
            for (int i = 0; i < 16; ++i) acc[m][n][i] = 0.f;

    const __bf16* hrow0 = hb + (size_t)rc0 * HIDN + kb;
    const __bf16* hrow1 = hb + (size_t)rc1 * HIDN + kb;

    // stage chunk starting at k-offset kc into buffer buf: wave w stages items w, w+4, ...
    auto stage = [&](int buf, int kc) {
#pragma unroll
        for (int j = w; j < ITEMS; j += 4) {
            const int n  = j % NT;
            const int kp = j / NT;
            const int p  = kp % PH;
            const int kk = kp / PH;
            const __bf16* g = w2t + (size_t)(n * 32 + lo5) * KP
                              + (size_t)(kb + kc + kk) * MI + p * 16 + hi * 8;
            gload_lds16(g, &sb[buf][j * 512]);
        }
    };

    stage(0, 0);
    HPack<CH> hc0 = *reinterpret_cast<const HPack<CH>*>(hrow0);
    HPack<CH> hc1 = *reinterpret_cast<const HPack<CH>*>(hrow1);

    for (int c = 0; c < NCH; ++c) {
        __syncthreads();                      // drains chunk-c staging (vmcnt) for all waves
        if (c + 1 < NCH) stage((c + 1) & 1, (c + 1) * CH);
        HPack<CH> hn0 = hc0, hn1 = hc1;
        if (c + 1 < NCH) {
            hn0 = *reinterpret_cast<const HPack<CH>*>(hrow0 + (c + 1) * CH);
            hn1 = *reinterpret_cast<const HPack<CH>*>(hrow1 + (c + 1) * CH);
        }
        const int cb = c & 1;
#pragma unroll
        for (int kk = 0; kk < CH; ++kk) {
            const float hv0 = (float)hc0.v[kk];
            const float hv1 = (float)hc1.v[kk];
#pragma unroll
            for (int p = 0; p < PH; ++p) {
                bf16x8 af0, af1;
#pragma unroll
                for (int j2 = 0; j2 < 4; ++j2) {
                    unsigned int u0 = xp0[p][j2];
                    float xl0 = __builtin_bit_cast(float, u0 << 16);
                    float xh0 = __builtin_bit_cast(float, u0 & 0xffff0000u);
                    af0[2 * j2]     = (__bf16)(hv0 * xl0);
                    af0[2 * j2 + 1] = (__bf16)(hv0 * xh0);
                    unsigned int u1 = xp1[p][j2];
                    float xl1 = __builtin_bit_cast(float, u1 << 16);
                    float xh1 = __builtin_bit_cast(float, u1 & 0xffff0000u);
                    af1[2 * j2]     = (__bf16)(hv1 * xl1);
                    af1[2 * j2 + 1] = (__bf16)(hv1 * xh1);
                }
#pragma unroll
                for (int n = 0; n < NT; ++n) {
                    const bf16x8 bv = *reinterpret_cast<const bf16x8*>(
                        &sb[cb][((kk * PH + p) * NT + n) * 512 + lane * 8]);
                    acc[0][n] = __builtin_amdgcn_mfma_f32_32x32x16_bf16(af0, bv, acc[0][n], 0, 0, 0);
                    acc[1][n] = __builtin_amdgcn_mfma_f32_32x32x16_bf16(af1, bv, acc[1][n], 0, 0, 0);
                }
            }
        }
        hc0 = hn0; hc1 = hn1;
    }

    // k == 128 tail (folded b2 term, hfac = 1) — only the last y-block, direct global B
    if (blockIdx.y == KSPLIT - 1) {
#pragma unroll
        for (int p = 0; p < PH; ++p) {
            bf16x8 af0, af1;
#pragma unroll
            for (int j2 = 0; j2 < 4; ++j2) {
                unsigned int u0 = xp0[p][j2];
                af0[2 * j2]     = __builtin_bit_cast(__bf16, (unsigned short)(u0 & 0xffffu));
                af0[2 * j2 + 1] = __builtin_bit_cast(__bf16, (unsigned short)(u0 >> 16));
                unsigned int u1 = xp1[p][j2];
                af1[2 * j2]     = __builtin_bit_cast(__bf16, (unsigned short)(u1 & 0xffffu));
                af1[2 * j2 + 1] = __builtin_bit_cast(__bf16, (unsigned short)(u1 >> 16));
            }
#pragma unroll
            for (int n = 0; n < NT; ++n) {
                const bf16x8 bv = *reinterpret_cast<const bf16x8*>(
                    w2t + (size_t)(n * 32 + lo5) * KP + (size_t)128 * MI + p * 16 + hi * 8);
                acc[0][n] = __builtin_amdgcn_mfma_f32_32x32x16_bf16(af0, bv, acc[0][n], 0, 0, 0);
                acc[1][n] = __builtin_amdgcn_mfma_f32_32x32x16_bf16(af1, bv, acc[1][n], 0, 0, 0);
            }
        }
    }

    // epilogue: C layout col = lane&31, row = (reg&3) + 8*(reg>>2) + 4*(lane>>5)
#pragma unroll
    for (int m = 0; m < 2; ++m) {
        const int ebase = e0 + m * 32;
#pragma unroll
        for (int q = 0; q < 4; ++q) {
#pragma unroll
            for (int a = 0; a < 4; ++a) {
                const int e = ebase + 4 * hi + 8 * q + a;
                if (e < NE) {
                    const int d = dst[e];
#pragma unroll
                    for (int n = 0; n < NT; ++n) {
                        const float v = (m == 0) ? acc[0][n][4 * q + a] : acc[1][n][4 * q + a];
                        atomicAdd(&out[(size_t)d * MO + n * 32 + lo5], v);
                    }
                }
            }
        }
    }
}

// ---------------- ELU in place ----------------
__global__ void k_elu(float* __restrict__ a, int n) {
    int i = blockIdx.x * 256 + threadIdx.x;
    if (i < n) a[i] = eluf(a[i]);
}

// ---------------- pool nodes -> subgraphs (sum + count) ----------------
__global__ void k_pool_s(const float* __restrict__ xi, const float* __restrict__ x,
                         const int* __restrict__ n2s, float* __restrict__ xs_sum,
                         float* __restrict__ cs) {
    int idx = blockIdx.x * 256 + threadIdx.x;
    if (idx >= NN * 72) return;
    int n = idx / 72, j = idx % 72;
    float v = (j < 64) ? xi[n * 64 + j] : x[n * 24 + 16 + (j - 64)];
    int s = n2s[n];
    atomicAdd(&xs_sum[s * 72 + j], v);
    if (j == 0) atomicAdd(&cs[s], 1.f);
}

// ---------------- pool subgraphs -> graphs (mean of means) ----------------
__global__ void k_pool_g(const float* __restrict__ xs_sum, const float* __restrict__ cs,
                         const int* __restrict__ s2g, float* __restrict__ xg_sum,
                         float* __restrict__ cg) {
    int idx = blockIdx.x * 256 + threadIdx.x;
    if (idx >= NS * 72) return;
    int s = idx / 72, j = idx % 72;
    float v = xs_sum[s * 72 + j] / fmaxf(cs[s], 1.f);
    int g = s2g[s];
    atomicAdd(&xg_sum[g * 72 + j], v);
    if (j == 0) atomicAdd(&cg[g], 1.f);
}

// ---------------- final MLP: 72 -> 36 -> 18 -> 1 ----------------
__global__ void k_fc(const float* __restrict__ xg_sum, const float* __restrict__ cg,
                     const float* __restrict__ w1, const float* __restrict__ b1,
                     const float* __restrict__ w2, const float* __restrict__ b2,
                     const float* __restrict__ w3, const float* __restrict__ b3,
                     float* __restrict__ out) {
    int g = threadIdx.x;
    if (g >= NG) return;
    float inv = 1.f / fmaxf(cg[g], 1.f);
    float v[72];
#pragma unroll
    for (int j = 0; j < 72; ++j) v[j] = xg_sum[g * 72 + j] * inv;
    float h1[36];
#pragma unroll
    for (int o = 0; o < 36; ++o) {
        float s = b1[o];
#pragma unroll
        for (int i = 0; i < 72; ++i) s = fmaf(v[i], w1[i * 36 + o], s);
        h1[o] = eluf(s);
    }
    float h2[18];
#pragma unroll
    for (int o = 0; o < 18; ++o) {
        float s = b2[o];
#pragma unroll
        for (int i = 0; i < 36; ++i) s = fmaf(h1[i], w2[i * 18 + o], s);
        h2[o] = eluf(s);
    }
    float s = b3[0];
#pragma unroll
    for (int i = 0; i < 18; ++i) s = fmaf(h2[i], w3[i], s);
    out[g] = s;
}

// ---------------- launcher ----------------
extern "C" void kernel_launch(void* const* d_in, const int* in_sizes, int n_in,
                              void* d_out, int out_size, void* d_ws, size_t ws_size,
                              hipStream_t stream) {
    const float* x   = (const float*)d_in[0];
    const int*   ei  = (const int*)d_in[1];
    const float* ea  = (const float*)d_in[2];
    const int*   n2s = (const int*)d_in[3];
    const int*   s2g = (const int*)d_in[4];
    const int* src = ei;
    const int* dst = ei + NE;

    const float* cw1[3]   = {(const float*)d_in[5],  (const float*)d_in[11], (const float*)d_in[17]};
    const float* cb1[3]   = {(const float*)d_in[6],  (const float*)d_in[12], (const float*)d_in[18]};
    const float* cw2[3]   = {(const float*)d_in[7],  (const float*)d_in[13], (const float*)d_in[19]};
    const float* cb2[3]   = {(const float*)d_in[8],  (const float*)d_in[14], (const float*)d_in[20]};
    const float* croot[3] = {(const float*)d_in[9],  (const float*)d_in[15], (const float*)d_in[21]};
    const float* cbias[3] = {(const float*)d_in[10], (const float*)d_in[16], (const float*)d_in[22]};
    const float* fc1w = (const float*)d_in[23];
    const float* fc1b = (const float*)d_in[24];
    const float* fc2w = (const float*)d_in[25];
    const float* fc2b = (const float*)d_in[26];
    const float* fc3w = (const float*)d_in[27];
    const float* fc3b = (const float*)d_in[28];

    // ---- workspace layout (bytes) ----
    char* W = (char*)d_ws;
    __bf16* hb    = (__bf16*)(W);                   // NE*128*2      = 15,360,000
    float*  xiA   = (float*)(W + 15360000);         // NN*64*4       =  5,120,000
    float*  xiB   = (float*)(W + 20480000);         // NN*64*4       =  5,120,000
    float*  xs_sum= (float*)(W + 25600000);         // NS*72*4       =    864,000
    float*  cs    = (float*)(W + 26464000);         // NS*4          =     12,000
    float*  xg_sum= (float*)(W + 26476000);         // NG*72*4       =     36,864
    float*  cg    = (float*)(W + 26512864);         // NG*4          =        512
    __bf16* w2t0  = (__bf16*)(W + 26513376);        // 32*2064*2     =    132,096
    __bf16* w2t1  = (__bf16*)(W + 26645472);        // 64*4128*2     =    528,384
    __bf16* w2t2  = (__bf16*)(W + 27173856);        // 64*8256*2     =  1,056,768
    // total 28,230,624 bytes

    // zero the pooling accumulators (contiguous region)
    hipMemsetAsync(xs_sum, 0, (size_t)(NS * 72 + NS) * 4 + (size_t)(NG * 72 + NG) * 4, stream);

    // prep: transposed bf16 W2 (with b2 folded as k==128)
    k_w2t<16, 32><<<(32 * 129 * 16 + 255) / 256, 256, 0, stream>>>(cw2[0], cb2[0], w2t0);
    k_w2t<32, 64><<<(64 * 129 * 32 + 255) / 256, 256, 0, stream>>>(cw2[1], cb2[1], w2t1);
    k_w2t<64, 64><<<(64 * 129 * 64 + 255) / 256, 256, 0, stream>>>(cw2[2], cb2[2], w2t2);

    const int EB = (NE + 255) / 256;

    // ---- layer 0: MI=16, MO=32, x (stride 24) -> xiB ----
    k_h<<<(NE * HIDN + 255) / 256, 256, 0, stream>>>(ea, cw1[0], cb1[0], hb);
    k_root<16, 32, 24><<<(NN * 32 + 255) / 256, 256, 0, stream>>>(x, croot[0], cbias[0], xiB);
    k_edge_mfma<16, 32, 24, 4, 16><<<dim3(EB, 4), 256, 0, stream>>>(x, hb, w2t0, src, dst, xiB);
    k_elu<<<(NN * 32 + 255) / 256, 256, 0, stream>>>(xiB, NN * 32);

    // ---- layer 1: MI=32, MO=64, xiB -> xiA ----
    k_h<<<(NE * HIDN + 255) / 256, 256, 0, stream>>>(ea, cw1[1], cb1[1], hb);
    k_root<32, 64, 32><<<(NN * 64 + 255) / 256, 256, 0, stream>>>(xiB, croot[1], cbias[1], xiA);
    k_edge_mfma<32, 64, 32, 4, 4><<<dim3(EB, 4), 256, 0, stream>>>(xiB, hb, w2t1, src, dst, xiA);
    k_elu<<<(NN * 64 + 255) / 256, 256, 0, stream>>>(xiA, NN * 64);

    // ---- layer 2: MI=64, MO=64, xiA -> xiB ----
    k_h<<<(NE * HIDN + 255) / 256, 256, 0, stream>>>(ea, cw1[2], cb1[2], hb);
    k_root<64, 64, 64><<<(NN * 64 + 255) / 256, 256, 0, stream>>>(xiA, croot[2], cbias[2], xiB);
    k_edge_mfma<64, 64, 64, 4, 2><<<dim3(EB, 4), 256, 0, stream>>>(xiA, hb, w2t2, src, dst, xiB);
    k_elu<<<(NN * 64 + 255) / 256, 256, 0, stream>>>(xiB, NN * 64);

    // ---- pooling + MLP ----
    k_pool_s<<<(NN * 72 + 255) / 256, 256, 0, stream>>>(xiB, x, n2s, xs_sum, cs);
    k_pool_g<<<(NS * 72 + 255) / 256, 256, 0, stream>>>(xs_sum, cs, s2g, xg_sum, cg);
    k_fc<<<1, 128, 0, stream>>>(xg_sum, cg, fc1w, fc1b, fc2w, fc2b, fc3w, fc3b, (float*)d_out);
}

// Round 6
// 490.702 us; speedup vs baseline: 1.6931x; 1.6931x over previous
//
#include <hip/hip_runtime.h>
#include <hip/hip_bf16.h>
#include <cmath>

#define NN 20000   // nodes
#define NE 60000   // edges
#define NS 3000    // subgraphs
#define NG 128     // graphs
#define HIDN 128   // hidden dim of edge-attr MLP

typedef float f32x16 __attribute__((ext_vector_type(16)));
typedef __bf16 bf16x8 __attribute__((ext_vector_type(8)));

__device__ __forceinline__ float eluf(float v) { return v > 0.f ? v : expm1f(v); }

__device__ __forceinline__ unsigned int packbf(float lo, float hi) {
    unsigned short l = __builtin_bit_cast(unsigned short, (__bf16)lo);
    unsigned short h = __builtin_bit_cast(unsigned short, (__bf16)hi);
    return ((unsigned int)h << 16) | l;
}

template <int CH>
struct alignas((CH * 2 < 8) ? (CH * 2) : 8) HPack { __bf16 v[CH]; };

// async global->LDS, 16B per lane; lds ptr must be wave-uniform (HW writes base + lane*16)
__device__ __forceinline__ void gload_lds16(const void* g, void* l) {
    __builtin_amdgcn_global_load_lds(
        (const __attribute__((address_space(1))) unsigned int*)g,
        (__attribute__((address_space(3))) unsigned int*)l, 16, 0, 0);
}

// ---------------- h = relu(ea @ w1 + b1)  (E x 128, bf16) ----------------
__global__ void k_h(const float* __restrict__ ea, const float* __restrict__ w1,
                    const float* __restrict__ b1, __bf16* __restrict__ hb) {
    int idx = blockIdx.x * 256 + threadIdx.x;
    if (idx >= NE * HIDN) return;
    int e = idx >> 7, j = idx & 127;
    float s = b1[j];
#pragma unroll
    for (int d = 0; d < 5; ++d) s = fmaf(ea[e * 5 + d], w1[d * HIDN + j], s);
    hb[idx] = (__bf16)fmaxf(s, 0.f);
}

// ---------------- w2t[o][kg] = bf16( kg<128*MI ? w2[kg*MO+o] : b2[(kg-128MI)*MO+o] ) ----------------
template <int MI, int MO>
__global__ void k_w2t(const float* __restrict__ w2, const float* __restrict__ b2,
                      __bf16* __restrict__ w2t) {
    constexpr int KP = 129 * MI;
    constexpr int KF = 128 * MI;
    int idx = blockIdx.x * 256 + threadIdx.x;
    if (idx >= MO * KP) return;
    int o = idx / KP, kg = idx % KP;
    float v = (kg < KF) ? w2[(size_t)kg * MO + o] : b2[(kg - KF) * MO + o];
    w2t[idx] = (__bf16)v;
}

// ---------------- out = xi @ root + bias  (initializes the agg buffer) ----------------
template <int MI, int MO, int XS>
__global__ void k_root(const float* __restrict__ xi, const float* __restrict__ root,
                       const float* __restrict__ bias, float* __restrict__ out) {
    int idx = blockIdx.x * 256 + threadIdx.x;
    if (idx >= NN * MO) return;
    int n = idx / MO, o = idx % MO;
    float s = bias[o];
#pragma unroll
    for (int i = 0; i < MI; ++i) s = fmaf(xi[(size_t)n * XS + i], root[i * MO + o], s);
    out[idx] = s;
}

// ---------------- MFMA edge kernel, LDS-staged B + LDS-staged h ----------------
// GEMM: msg[e,o] = sum_kg G[e,kg]*w2t[o][kg],  G[e, k*MI+i] = hfac(e,k)*xi[src[e],i]
// B staged in LDS via global_load_lds (double-buffered chunks); h staged ONCE per block
// (coalesced, single-pass) into padded LDS; k-loop h reads are LDS broadcasts.
// Wave = 64 edges (2 M-tiles of 32) x full MO. K split across blockIdx.y.
template <int MI, int MO, int XS, int KSPLIT, int CH>
__global__ __launch_bounds__(256, 3) void k_edge_mfma(
    const float* __restrict__ xi, const __bf16* __restrict__ hb,
    const __bf16* __restrict__ w2t,
    const int* __restrict__ src, const int* __restrict__ dst,
    float* __restrict__ out) {
    constexpr int PH  = MI / 16;        // K-steps per k value
    constexpr int KP  = 129 * MI;       // w2t row length
    constexpr int NT  = MO / 32;        // N tiles
    constexpr int KCH = 128 / KSPLIT;   // k values per y-block (main loop)
    constexpr int NCH = KCH / CH;       // chunks per y-block
    constexpr int ITEMS = CH * PH * NT; // 1KB items per chunk
    static_assert(ITEMS == 16, "keep B-LDS at 2x16KB");
    constexpr int SHP = KCH + 4;        // padded h row stride (elements; 72B rows: 8B-aligned, 2-way banks)

    __shared__ __align__(16) __bf16 sb[2][ITEMS * 512];
    __shared__ __align__(16) __bf16 sh[256 * SHP];

    const int lane = threadIdx.x & 63;
    const int w    = threadIdx.x >> 6;
    const int lo5  = lane & 31;
    const int hi   = lane >> 5;
    const int eb   = blockIdx.x * 256;
    const int e0   = eb + w * 64;       // may exceed NE for tail waves: no early return (barriers)

    const int kb = KCH * (int)blockIdx.y;

    // ---- stage h to LDS: single coalesced pass (8 threads cover one edge's KCH slice) ----
    {
        constexpr int SEGS = KCH / 4;   // 8B segments per edge
        for (int idx = threadIdx.x; idx < 256 * SEGS; idx += 256) {
            const int el = idx / SEGS, sg = idx % SEGS;
            const int e  = eb + el;
            const int ec = (e < NE) ? e : 0;
            *reinterpret_cast<uint2*>(&sh[el * SHP + sg * 4]) =
                *reinterpret_cast<const uint2*>(hb + (size_t)ec * HIDN + kb + sg * 4);
        }
    }

    int r0 = e0 + lo5, r1 = e0 + 32 + lo5;
    const int rc0 = (r0 < NE) ? r0 : 0;
    const int rc1 = (r1 < NE) ? r1 : 0;
    const int s0 = src[rc0];
    const int s1 = src[rc1];

    // gather this lane's x fragment subset into registers, packed bf16 (2 per uint)
    unsigned int xp0[PH][4], xp1[PH][4];
    {
        const float* xb0 = xi + (size_t)s0 * XS + hi * 8;
        const float* xb1 = xi + (size_t)s1 * XS + hi * 8;
#pragma unroll
        for (int p = 0; p < PH; ++p) {
            float4 a = *reinterpret_cast<const float4*>(xb0 + p * 16);
            float4 b = *reinterpret_cast<const float4*>(xb0 + p * 16 + 4);
            xp0[p][0] = packbf(a.x, a.y); xp0[p][1] = packbf(a.z, a.w);
            xp0[p][2] = packbf(b.x, b.y); xp0[p][3] = packbf(b.z, b.w);
            float4 c = *reinterpret_cast<const float4*>(xb1 + p * 16);
            float4 d = *reinterpret_cast<const float4*>(xb1 + p * 16 + 4);
            xp1[p][0] = packbf(c.x, c.y); xp1[p][1] = packbf(c.z, c.w);
            xp1[p][2] = packbf(d.x, d.y); xp1[p][3] = packbf(d.z, d.w);
        }
    }

    f32x16 acc[2][NT];
#pragma unroll
    for (int m = 0; m < 2; ++m)
#pragma unroll
        for (int n = 0; n < NT; ++n)
#pragma unroll
            for (int i = 0; i < 16; ++i) acc[m][n][i] = 0.f;

    // stage B chunk starting at k-offset kc into buffer buf: wave w stages items w, w+4, ...
    auto stage = [&](int buf, int kc) {
#pragma unroll
        for (int j = w; j < ITEMS; j += 4) {
            const int n  = j % NT;
            const int kp = j / NT;
            const int p  = kp % PH;
            const int kk = kp / PH;
            const __bf16* g = w2t + (size_t)(n * 32 + lo5) * KP
                              + (size_t)(kb + kc + kk) * MI + p * 16 + hi * 8;
            gload_lds16(g, &sb[buf][j * 512]);
        }
    };

    stage(0, 0);

    const __bf16* hl0 = &sh[(w * 64 + lo5) * SHP];        // lanes 0-31 / 32-63 same addr -> broadcast
    const __bf16* hl1 = &sh[(w * 64 + 32 + lo5) * SHP];

    for (int c = 0; c < NCH; ++c) {
        __syncthreads();                      // drains chunk-c B staging (+h writes on c==0)
        if (c + 1 < NCH) stage((c + 1) & 1, (c + 1) * CH);
        const int cb = c & 1;
        const int kc = c * CH;
        HPack<CH> hc0 = *reinterpret_cast<const HPack<CH>*>(hl0 + kc);
        HPack<CH> hc1 = *reinterpret_cast<const HPack<CH>*>(hl1 + kc);
#pragma unroll
        for (int p = 0; p < PH; ++p) {
            // k-invariant unpack of x fragments (hoisted out of kk loop)
            float xf0[8], xf1[8];
#pragma unroll
            for (int j2 = 0; j2 < 4; ++j2) {
                const unsigned int u0 = xp0[p][j2];
                xf0[2 * j2]     = __builtin_bit_cast(float, u0 << 16);
                xf0[2 * j2 + 1] = __builtin_bit_cast(float, u0 & 0xffff0000u);
                const unsigned int u1 = xp1[p][j2];
                xf1[2 * j2]     = __builtin_bit_cast(float, u1 << 16);
                xf1[2 * j2 + 1] = __builtin_bit_cast(float, u1 & 0xffff0000u);
            }
#pragma unroll
            for (int kk = 0; kk < CH; ++kk) {
                const float hv0 = (float)hc0.v[kk];
                const float hv1 = (float)hc1.v[kk];
                bf16x8 af0, af1;
#pragma unroll
                for (int j = 0; j < 8; ++j) {
                    af0[j] = (__bf16)(hv0 * xf0[j]);
                    af1[j] = (__bf16)(hv1 * xf1[j]);
                }
#pragma unroll
                for (int n = 0; n < NT; ++n) {
                    const bf16x8 bv = *reinterpret_cast<const bf16x8*>(
                        &sb[cb][((kk * PH + p) * NT + n) * 512 + lane * 8]);
                    acc[0][n] = __builtin_amdgcn_mfma_f32_32x32x16_bf16(af0, bv, acc[0][n], 0, 0, 0);
                    acc[1][n] = __builtin_amdgcn_mfma_f32_32x32x16_bf16(af1, bv, acc[1][n], 0, 0, 0);
                }
            }
        }
    }

    // k == 128 tail (folded b2 term, hfac = 1) — only the last y-block, direct global B
    if (blockIdx.y == KSPLIT - 1) {
#pragma unroll
        for (int p = 0; p < PH; ++p) {
            bf16x8 af0, af1;
#pragma unroll
            for (int j2 = 0; j2 < 4; ++j2) {
                const unsigned int u0 = xp0[p][j2];
                af0[2 * j2]     = __builtin_bit_cast(__bf16, (unsigned short)(u0 & 0xffffu));
                af0[2 * j2 + 1] = __builtin_bit_cast(__bf16, (unsigned short)(u0 >> 16));
                const unsigned int u1 = xp1[p][j2];
                af1[2 * j2]     = __builtin_bit_cast(__bf16, (unsigned short)(u1 & 0xffffu));
                af1[2 * j2 + 1] = __builtin_bit_cast(__bf16, (unsigned short)(u1 >> 16));
            }
#pragma unroll
            for (int n = 0; n < NT; ++n) {
                const bf16x8 bv = *reinterpret_cast<const bf16x8*>(
                    w2t + (size_t)(n * 32 + lo5) * KP + (size_t)128 * MI + p * 16 + hi * 8);
                acc[0][n] = __builtin_amdgcn_mfma_f32_32x32x16_bf16(af0, bv, acc[0][n], 0, 0, 0);
                acc[1][n] = __builtin_amdgcn_mfma_f32_32x32x16_bf16(af1, bv, acc[1][n], 0, 0, 0);
            }
        }
    }

    // epilogue: C layout col = lane&31, row = (reg&3) + 8*(reg>>2) + 4*(lane>>5)
#pragma unroll
    for (int m = 0; m < 2; ++m) {
        const int ebase = e0 + m * 32;
#pragma unroll
        for (int q = 0; q < 4; ++q) {
#pragma unroll
            for (int a = 0; a < 4; ++a) {
                const int e = ebase + 4 * hi + 8 * q + a;
                if (e < NE) {
                    const int d = dst[e];
#pragma unroll
                    for (int n = 0; n < NT; ++n) {
                        const float v = (m == 0) ? acc[0][n][4 * q + a] : acc[1][n][4 * q + a];
                        atomicAdd(&out[(size_t)d * MO + n * 32 + lo5], v);
                    }
                }
            }
        }
    }
}

// ---------------- ELU in place ----------------
__global__ void k_elu(float* __restrict__ a, int n) {
    int i = blockIdx.x * 256 + threadIdx.x;
    if (i < n) a[i] = eluf(a[i]);
}

// ---------------- pool nodes -> subgraphs (sum + count) ----------------
__global__ void k_pool_s(const float* __restrict__ xi, const float* __restrict__ x,
                         const int* __restrict__ n2s, float* __restrict__ xs_sum,
                         float* __restrict__ cs) {
    int idx = blockIdx.x * 256 + threadIdx.x;
    if (idx >= NN * 72) return;
    int n = idx / 72, j = idx % 72;
    float v = (j < 64) ? xi[n * 64 + j] : x[n * 24 + 16 + (j - 64)];
    int s = n2s[n];
    atomicAdd(&xs_sum[s * 72 + j], v);
    if (j == 0) atomicAdd(&cs[s], 1.f);
}

// ---------------- pool subgraphs -> graphs (mean of means) ----------------
__global__ void k_pool_g(const float* __restrict__ xs_sum, const float* __restrict__ cs,
                         const int* __restrict__ s2g, float* __restrict__ xg_sum,
                         float* __restrict__ cg) {
    int idx = blockIdx.x * 256 + threadIdx.x;
    if (idx >= NS * 72) return;
    int s = idx / 72, j = idx % 72;
    float v = xs_sum[s * 72 + j] / fmaxf(cs[s], 1.f);
    int g = s2g[s];
    atomicAdd(&xg_sum[g * 72 + j], v);
    if (j == 0) atomicAdd(&cg[g], 1.f);
}

// ---------------- final MLP: 72 -> 36 -> 18 -> 1 ----------------
__global__ void k_fc(const float* __restrict__ xg_sum, const float* __restrict__ cg,
                     const float* __restrict__ w1, const float* __restrict__ b1,
                     const float* __restrict__ w2, const float* __restrict__ b2,
                     const float* __restrict__ w3, const float* __restrict__ b3,
                     float* __restrict__ out) {
    int g = threadIdx.x;
    if (g >= NG) return;
    float inv = 1.f / fmaxf(cg[g], 1.f);
    float v[72];
#pragma unroll
    for (int j = 0; j < 72; ++j) v[j] = xg_sum[g * 72 + j] * inv;
    float h1[36];
#pragma unroll
    for (int o = 0; o < 36; ++o) {
        float s = b1[o];
#pragma unroll
        for (int i = 0; i < 72; ++i) s = fmaf(v[i], w1[i * 36 + o], s);
        h1[o] = eluf(s);
    }
    float h2[18];
#pragma unroll
    for (int o = 0; o < 18; ++o) {
        float s = b2[o];
#pragma unroll
        for (int i = 0; i < 36; ++i) s = fmaf(h1[i], w2[i * 18 + o], s);
        h2[o] = eluf(s);
    }
    float s = b3[0];
#pragma unroll
    for (int i = 0; i < 18; ++i) s = fmaf(h2[i], w3[i], s);
    out[g] = s;
}

// ---------------- launcher ----------------
extern "C" void kernel_launch(void* const* d_in, const int* in_sizes, int n_in,
                              void* d_out, int out_size, void* d_ws, size_t ws_size,
                              hipStream_t stream) {
    const float* x   = (const float*)d_in[0];
    const int*   ei  = (const int*)d_in[1];
    const float* ea  = (const float*)d_in[2];
    const int*   n2s = (const int*)d_in[3];
    const int*   s2g = (const int*)d_in[4];
    const int* src = ei;
    const int* dst = ei + NE;

    const float* cw1[3]   = {(const float*)d_in[5],  (const float*)d_in[11], (const float*)d_in[17]};
    const float* cb1[3]   = {(const float*)d_in[6],  (const float*)d_in[12], (const float*)d_in[18]};
    const float* cw2[3]   = {(const float*)d_in[7],  (const float*)d_in[13], (const float*)d_in[19]};
    const float* cb2[3]   = {(const float*)d_in[8],  (const float*)d_in[14], (const float*)d_in[20]};
    const float* croot[3] = {(const float*)d_in[9],  (const float*)d_in[15], (const float*)d_in[21]};
    const float* cbias[3] = {(const float*)d_in[10], (const float*)d_in[16], (const float*)d_in[22]};
    const float* fc1w = (const float*)d_in[23];
    const float* fc1b = (const float*)d_in[24];
    const float* fc2w = (const float*)d_in[25];
    const float* fc2b = (const float*)d_in[26];
    const float* fc3w = (const float*)d_in[27];
    const float* fc3b = (const float*)d_in[28];

    // ---- workspace layout (bytes) ----
    char* W = (char*)d_ws;
    __bf16* hb    = (__bf16*)(W);                   // NE*128*2      = 15,360,000
    float*  xiA   = (float*)(W + 15360000);         // NN*64*4       =  5,120,000
    float*  xiB   = (float*)(W + 20480000);         // NN*64*4       =  5,120,000
    float*  xs_sum= (float*)(W + 25600000);         // NS*72*4       =    864,000
    float*  cs    = (float*)(W + 26464000);         // NS*4          =     12,000
    float*  xg_sum= (float*)(W + 26476000);         // NG*72*4       =     36,864
    float*  cg    = (float*)(W + 26512864);         // NG*4          =        512
    __bf16* w2t0  = (__bf16*)(W + 26513376);        // 32*2064*2     =    132,096
    __bf16* w2t1  = (__bf16*)(W + 26645472);        // 64*4128*2     =    528,384
    __bf16* w2t2  = (__bf16*)(W + 27173856);        // 64*8256*2     =  1,056,768
    // total 28,230,624 bytes

    // zero the pooling accumulators (contiguous region)
    hipMemsetAsync(xs_sum, 0, (size_t)(NS * 72 + NS) * 4 + (size_t)(NG * 72 + NG) * 4, stream);

    // prep: transposed bf16 W2 (with b2 folded as k==128)
    k_w2t<16, 32><<<(32 * 129 * 16 + 255) / 256, 256, 0, stream>>>(cw2[0], cb2[0], w2t0);
    k_w2t<32, 64><<<(64 * 129 * 32 + 255) / 256, 256, 0, stream>>>(cw2[1], cb2[1], w2t1);
    k_w2t<64, 64><<<(64 * 129 * 64 + 255) / 256, 256, 0, stream>>>(cw2[2], cb2[2], w2t2);

    const int EB = (NE + 255) / 256;

    // ---- layer 0: MI=16, MO=32, x (stride 24) -> xiB ----
    k_h<<<(NE * HIDN + 255) / 256, 256, 0, stream>>>(ea, cw1[0], cb1[0], hb);
    k_root<16, 32, 24><<<(NN * 32 + 255) / 256, 256, 0, stream>>>(x, croot[0], cbias[0], xiB);
    k_edge_mfma<16, 32, 24, 4, 16><<<dim3(EB, 4), 256, 0, stream>>>(x, hb, w2t0, src, dst, xiB);
    k_elu<<<(NN * 32 + 255) / 256, 256, 0, stream>>>(xiB, NN * 32);

    // ---- layer 1: MI=32, MO=64, xiB -> xiA ----
    k_h<<<(NE * HIDN + 255) / 256, 256, 0, stream>>>(ea, cw1[1], cb1[1], hb);
    k_root<32, 64, 32><<<(NN * 64 + 255) / 256, 256, 0, stream>>>(xiB, croot[1], cbias[1], xiA);
    k_edge_mfma<32, 64, 32, 4, 4><<<dim3(EB, 4), 256, 0, stream>>>(xiB, hb, w2t1, src, dst, xiA);
    k_elu<<<(NN * 64 + 255) / 256, 256, 0, stream>>>(xiA, NN * 64);

    // ---- layer 2: MI=64, MO=64, xiA -> xiB ----
    k_h<<<(NE * HIDN + 255) / 256, 256, 0, stream>>>(ea, cw1[2], cb1[2], hb);
    k_root<64, 64, 64><<<(NN * 64 + 255) / 256, 256, 0, stream>>>(xiA, croot[2], cbias[2], xiB);
    k_edge_mfma<64, 64, 64, 4, 2><<<dim3(EB, 4), 256, 0, stream>>>(xiA, hb, w2t2, src, dst, xiB);
    k_elu<<<(NN * 64 + 255) / 256, 256, 0, stream>>>(xiB, NN * 64);

    // ---- pooling + MLP ----
    k_pool_s<<<(NN * 72 + 255) / 256, 256, 0, stream>>>(xiB, x, n2s, xs_sum, cs);
    k_pool_g<<<(NS * 72 + 255) / 256, 256, 0, stream>>>(xs_sum, cs, s2g, xg_sum, cg);
    k_fc<<<1, 128, 0, stream>>>(xg_sum, cg, fc1w, fc1b, fc2w, fc2b, fc3w, fc3b, (float*)d_out);
}

// Round 7
// 424.751 us; speedup vs baseline: 1.9559x; 1.1553x over previous
//
#include <hip/hip_runtime.h>
#include <hip/hip_bf16.h>
#include <cmath>

#define NN 20000   // nodes
#define NE 60000   // edges
#define NS 3000    // subgraphs
#define NG 128     // graphs
#define HIDN 128   // hidden dim of edge-attr MLP

typedef float f32x16 __attribute__((ext_vector_type(16)));
typedef __bf16 bf16x8 __attribute__((ext_vector_type(8)));

__device__ __forceinline__ float eluf(float v) { return v > 0.f ? v : expm1f(v); }

__device__ __forceinline__ unsigned int packbf(float lo, float hi) {
    unsigned short l = __builtin_bit_cast(unsigned short, (__bf16)lo);
    unsigned short h = __builtin_bit_cast(unsigned short, (__bf16)hi);
    return ((unsigned int)h << 16) | l;
}

template <int CH>
struct alignas((CH * 2 < 16) ? (CH * 2) : 16) HPack { __bf16 v[CH]; };

// async global->LDS, 16B per lane; lds ptr must be wave-uniform (HW writes base + lane*16)
__device__ __forceinline__ void gload_lds16(const void* g, void* l) {
    __builtin_amdgcn_global_load_lds(
        (const __attribute__((address_space(1))) unsigned int*)g,
        (__attribute__((address_space(3))) unsigned int*)l, 16, 0, 0);
}

// ================= one-time edge sort by dst (counting sort) =================
__global__ void k_hist(const int* __restrict__ dst, int* __restrict__ deg) {
    int e = blockIdx.x * 256 + threadIdx.x;
    if (e < NE) atomicAdd(&deg[dst[e]], 1);
}

// single block, 1024 threads: exclusive prefix over NN bins -> rowptr[NN+1]
__global__ void k_scan(const int* __restrict__ deg, int* __restrict__ rowptr) {
    __shared__ int buf[1024];
    const int t = threadIdx.x;
    if (t == 0) rowptr[0] = 0;
    int carry = 0;
    for (int base = 0; base < NN; base += 1024) {
        int v = (base + t < NN) ? deg[base + t] : 0;
        buf[t] = v;
        __syncthreads();
        for (int off = 1; off < 1024; off <<= 1) {
            int add = (t >= off) ? buf[t - off] : 0;
            __syncthreads();
            buf[t] += add;
            __syncthreads();
        }
        if (base + t < NN) rowptr[base + t + 1] = carry + buf[t];
        int total = buf[1023];
        __syncthreads();
        carry += total;
    }
}

__global__ void k_scatter(const int* __restrict__ src, const int* __restrict__ dst,
                          const int* __restrict__ rowptr, int* __restrict__ tmp,
                          int* __restrict__ eord, int* __restrict__ srcS) {
    int e = blockIdx.x * 256 + threadIdx.x;
    if (e >= NE) return;
    int d = dst[e];
    int pos = rowptr[d] + atomicAdd(&tmp[d], 1);
    eord[pos] = e;
    srcS[pos] = src[e];
}

// ---------------- h = relu(ea @ w1 + b1) in SORTED edge order (E x 128, bf16) ----------------
__global__ void k_h(const int* __restrict__ eord, const float* __restrict__ ea,
                    const float* __restrict__ w1, const float* __restrict__ b1,
                    __bf16* __restrict__ hS) {
    int idx = blockIdx.x * 256 + threadIdx.x;
    if (idx >= NE * HIDN) return;
    int jj = idx >> 7, j = idx & 127;
    int e = eord[jj];
    float s = b1[j];
#pragma unroll
    for (int d = 0; d < 5; ++d) s = fmaf(ea[e * 5 + d], w1[d * HIDN + j], s);
    hS[idx] = (__bf16)fmaxf(s, 0.f);
}

// ---------------- w2t[o][kg] = bf16( kg<128*MI ? w2[kg*MO+o] : b2[(kg-128MI)*MO+o] ) ----------------
template <int MI, int MO>
__global__ void k_w2t(const float* __restrict__ w2, const float* __restrict__ b2,
                      __bf16* __restrict__ w2t) {
    constexpr int KP = 129 * MI;
    constexpr int KF = 128 * MI;
    int idx = blockIdx.x * 256 + threadIdx.x;
    if (idx >= MO * KP) return;
    int o = idx / KP, kg = idx % KP;
    float v = (kg < KF) ? w2[(size_t)kg * MO + o] : b2[(kg - KF) * MO + o];
    w2t[idx] = (__bf16)v;
}

// ---------------- MFMA edge kernel: sorted edges, plain stores, N-split ----------------
// msg[j,o] = sum_kg G[j,kg]*w2t[o][kg],  G[j, k*MI+i] = hfac(j,k)*xi[srcS[j],i]
// Wave = 64 edges (2 M-tiles) x 32 outputs (blockIdx.y N-slice). Full K per wave.
// B double-buffered in LDS (16KB chunks) via global_load_lds; h read direct (sorted rows).
template <int MI, int MO, int XS>
__global__ __launch_bounds__(128, 4) void k_edge2(
    const float* __restrict__ xi, const __bf16* __restrict__ hS,
    const __bf16* __restrict__ w2t, const int* __restrict__ srcS,
    float* __restrict__ msg) {
    constexpr int PH  = MI / 16;     // K-steps per k value
    constexpr int KP  = 129 * MI;    // w2t row length
    constexpr int CH  = 16 / PH;     // k values per chunk (ITEMS = CH*PH = 16)
    constexpr int NCH = 128 / CH;    // chunks

    __shared__ __align__(16) __bf16 sb[2][16 * 512];   // 2 x 16KB

    const int lane = threadIdx.x & 63;
    const int w    = threadIdx.x >> 6;   // 0/1
    const int lo5  = lane & 31;
    const int hi   = lane >> 5;
    const int e0   = blockIdx.x * 128 + w * 64;
    const int ns   = blockIdx.y;

    const int r0 = e0 + lo5, r1 = e0 + 32 + lo5;
    const int rc0 = (r0 < NE) ? r0 : 0;
    const int rc1 = (r1 < NE) ? r1 : 0;
    const int s0 = srcS[rc0];
    const int s1 = srcS[rc1];

    // gather this lane's x fragment subset, packed bf16 (2 per uint)
    unsigned int xp0[PH][4], xp1[PH][4];
    {
        const float* xb0 = xi + (size_t)s0 * XS + hi * 8;
        const float* xb1 = xi + (size_t)s1 * XS + hi * 8;
#pragma unroll
        for (int p = 0; p < PH; ++p) {
            float4 a = *reinterpret_cast<const float4*>(xb0 + p * 16);
            float4 b = *reinterpret_cast<const float4*>(xb0 + p * 16 + 4);
            xp0[p][0] = packbf(a.x, a.y); xp0[p][1] = packbf(a.z, a.w);
            xp0[p][2] = packbf(b.x, b.y); xp0[p][3] = packbf(b.z, b.w);
            float4 c = *reinterpret_cast<const float4*>(xb1 + p * 16);
            float4 d = *reinterpret_cast<const float4*>(xb1 + p * 16 + 4);
            xp1[p][0] = packbf(c.x, c.y); xp1[p][1] = packbf(c.z, c.w);
            xp1[p][2] = packbf(d.x, d.y); xp1[p][3] = packbf(d.z, d.w);
        }
    }

    f32x16 acc0, acc1;
#pragma unroll
    for (int i = 0; i < 16; ++i) { acc0[i] = 0.f; acc1[i] = 0.f; }

    const __bf16* bbase = w2t + (size_t)(ns * 32 + lo5) * KP + hi * 8;
    const __bf16* h0 = hS + (size_t)rc0 * HIDN;
    const __bf16* h1 = hS + (size_t)rc1 * HIDN;

    // stage 16 x 1KB items; wave w stages items w, w+2, ...
    auto stage = [&](int buf, int kc) {
#pragma unroll
        for (int jj = 0; jj < 8; ++jj) {
            const int j  = w + jj * 2;
            const int kk = j / PH;
            const int p  = j % PH;
            gload_lds16(bbase + (size_t)(kc + kk) * MI + p * 16, &sb[buf][j * 512]);
        }
    };

    stage(0, 0);
    HPack<CH> hc0 = *reinterpret_cast<const HPack<CH>*>(h0);
    HPack<CH> hc1 = *reinterpret_cast<const HPack<CH>*>(h1);

    for (int c = 0; c < NCH; ++c) {
        __syncthreads();                    // drains chunk-c staging for both waves
        if (c + 1 < NCH) stage((c + 1) & 1, (c + 1) * CH);
        HPack<CH> hn0 = hc0, hn1 = hc1;
        if (c + 1 < NCH) {
            hn0 = *reinterpret_cast<const HPack<CH>*>(h0 + (c + 1) * CH);
            hn1 = *reinterpret_cast<const HPack<CH>*>(h1 + (c + 1) * CH);
        }
        const __bf16* sbc = &sb[c & 1][0];
#pragma unroll
        for (int p = 0; p < PH; ++p) {
            float xf0[8], xf1[8];
#pragma unroll
            for (int j2 = 0; j2 < 4; ++j2) {
                const unsigned int u0 = xp0[p][j2];
                xf0[2 * j2]     = __builtin_bit_cast(float, u0 << 16);
                xf0[2 * j2 + 1] = __builtin_bit_cast(float, u0 & 0xffff0000u);
                const unsigned int u1 = xp1[p][j2];
                xf1[2 * j2]     = __builtin_bit_cast(float, u1 << 16);
                xf1[2 * j2 + 1] = __builtin_bit_cast(float, u1 & 0xffff0000u);
            }
#pragma unroll
            for (int kk = 0; kk < CH; ++kk) {
                const float hv0 = (float)hc0.v[kk];
                const float hv1 = (float)hc1.v[kk];
                bf16x8 af0, af1;
#pragma unroll
                for (int j = 0; j < 8; ++j) {
                    af0[j] = (__bf16)(hv0 * xf0[j]);
                    af1[j] = (__bf16)(hv1 * xf1[j]);
                }
                const bf16x8 bv = *reinterpret_cast<const bf16x8*>(
                    &sbc[(kk * PH + p) * 512 + lane * 8]);
                acc0 = __builtin_amdgcn_mfma_f32_32x32x16_bf16(af0, bv, acc0, 0, 0, 0);
                acc1 = __builtin_amdgcn_mfma_f32_32x32x16_bf16(af1, bv, acc1, 0, 0, 0);
            }
        }
        hc0 = hn0; hc1 = hn1;
    }

    // k == 128 tail (folded b2 term, hfac = 1) — direct global B
#pragma unroll
    for (int p = 0; p < PH; ++p) {
        bf16x8 af0, af1;
#pragma unroll
        for (int j2 = 0; j2 < 4; ++j2) {
            const unsigned int u0 = xp0[p][j2];
            af0[2 * j2]     = __builtin_bit_cast(__bf16, (unsigned short)(u0 & 0xffffu));
            af0[2 * j2 + 1] = __builtin_bit_cast(__bf16, (unsigned short)(u0 >> 16));
            const unsigned int u1 = xp1[p][j2];
            af1[2 * j2]     = __builtin_bit_cast(__bf16, (unsigned short)(u1 & 0xffffu));
            af1[2 * j2 + 1] = __builtin_bit_cast(__bf16, (unsigned short)(u1 >> 16));
        }
        const bf16x8 bv = *reinterpret_cast<const bf16x8*>(bbase + (size_t)128 * MI + p * 16);
        acc0 = __builtin_amdgcn_mfma_f32_32x32x16_bf16(af0, bv, acc0, 0, 0, 0);
        acc1 = __builtin_amdgcn_mfma_f32_32x32x16_bf16(af1, bv, acc1, 0, 0, 0);
    }

    // store: C layout col = lane&31, row = (reg&3) + 8*(reg>>2) + 4*(lane>>5)
#pragma unroll
    for (int m = 0; m < 2; ++m) {
#pragma unroll
        for (int q = 0; q < 4; ++q) {
#pragma unroll
            for (int a = 0; a < 4; ++a) {
                const int e = e0 + m * 32 + 4 * hi + 8 * q + a;
                if (e < NE) {
                    const float v = (m == 0) ? acc0[4 * q + a] : acc1[4 * q + a];
                    msg[(size_t)e * MO + ns * 32 + lo5] = v;
                }
            }
        }
    }
}

// ---------------- agg: out[n,o] = elu( bias[o] + xi@root + sum_{j in CSR[n]} msg[j,o] ) ----------------
template <int MI, int MO, int XS>
__global__ void k_agg(const float* __restrict__ msg, const int* __restrict__ rowptr,
                      const float* __restrict__ xi, const float* __restrict__ root,
                      const float* __restrict__ bias, float* __restrict__ out) {
    int idx = blockIdx.x * 256 + threadIdx.x;
    if (idx >= NN * MO) return;
    int n = idx / MO, o = idx % MO;
    float s = bias[o];
#pragma unroll
    for (int i = 0; i < MI; ++i) s = fmaf(xi[(size_t)n * XS + i], root[i * MO + o], s);
    const int j0 = rowptr[n], j1 = rowptr[n + 1];
    for (int j = j0; j < j1; ++j) s += msg[(size_t)j * MO + o];
    out[idx] = eluf(s);
}

// ---------------- pool nodes -> subgraphs (sum + count) ----------------
__global__ void k_pool_s(const float* __restrict__ xi, const float* __restrict__ x,
                         const int* __restrict__ n2s, float* __restrict__ xs_sum,
                         float* __restrict__ cs) {
    int idx = blockIdx.x * 256 + threadIdx.x;
    if (idx >= NN * 72) return;
    int n = idx / 72, j = idx % 72;
    float v = (j < 64) ? xi[n * 64 + j] : x[n * 24 + 16 + (j - 64)];
    int s = n2s[n];
    atomicAdd(&xs_sum[s * 72 + j], v);
    if (j == 0) atomicAdd(&cs[s], 1.f);
}

// ---------------- pool subgraphs -> graphs (mean of means) ----------------
__global__ void k_pool_g(const float* __restrict__ xs_sum, const float* __restrict__ cs,
                         const int* __restrict__ s2g, float* __restrict__ xg_sum,
                         float* __restrict__ cg) {
    int idx = blockIdx.x * 256 + threadIdx.x;
    if (idx >= NS * 72) return;
    int s = idx / 72, j = idx % 72;
    float v = xs_sum[s * 72 + j] / fmaxf(cs[s], 1.f);
    int g = s2g[s];
    atomicAdd(&xg_sum[g * 72 + j], v);
    if (j == 0) atomicAdd(&cg[g], 1.f);
}

// ---------------- final MLP: 72 -> 36 -> 18 -> 1 ----------------
__global__ void k_fc(const float* __restrict__ xg_sum, const float* __restrict__ cg,
                     const float* __restrict__ w1, const float* __restrict__ b1,
                     const float* __restrict__ w2, const float* __restrict__ b2,
                     const float* __restrict__ w3, const float* __restrict__ b3,
                     float* __restrict__ out) {
    int g = threadIdx.x;
    if (g >= NG) return;
    float inv = 1.f / fmaxf(cg[g], 1.f);
    float v[72];
#pragma unroll
    for (int j = 0; j < 72; ++j) v[j] = xg_sum[g * 72 + j] * inv;
    float h1[36];
#pragma unroll
    for (int o = 0; o < 36; ++o) {
        float s = b1[o];
#pragma unroll
        for (int i = 0; i < 72; ++i) s = fmaf(v[i], w1[i * 36 + o], s);
        h1[o] = eluf(s);
    }
    float h2[18];
#pragma unroll
    for (int o = 0; o < 18; ++o) {
        float s = b2[o];
#pragma unroll
        for (int i = 0; i < 36; ++i) s = fmaf(h1[i], w2[i * 18 + o], s);
        h2[o] = eluf(s);
    }
    float s = b3[0];
#pragma unroll
    for (int i = 0; i < 18; ++i) s = fmaf(h2[i], w3[i], s);
    out[g] = s;
}

// ---------------- launcher ----------------
extern "C" void kernel_launch(void* const* d_in, const int* in_sizes, int n_in,
                              void* d_out, int out_size, void* d_ws, size_t ws_size,
                              hipStream_t stream) {
    const float* x   = (const float*)d_in[0];
    const int*   ei  = (const int*)d_in[1];
    const float* ea  = (const float*)d_in[2];
    const int*   n2s = (const int*)d_in[3];
    const int*   s2g = (const int*)d_in[4];
    const int* src = ei;
    const int* dst = ei + NE;

    const float* cw1[3]   = {(const float*)d_in[5],  (const float*)d_in[11], (const float*)d_in[17]};
    const float* cb1[3]   = {(const float*)d_in[6],  (const float*)d_in[12], (const float*)d_in[18]};
    const float* cw2[3]   = {(const float*)d_in[7],  (const float*)d_in[13], (const float*)d_in[19]};
    const float* cb2[3]   = {(const float*)d_in[8],  (const float*)d_in[14], (const float*)d_in[20]};
    const float* croot[3] = {(const float*)d_in[9],  (const float*)d_in[15], (const float*)d_in[21]};
    const float* cbias[3] = {(const float*)d_in[10], (const float*)d_in[16], (const float*)d_in[22]};
    const float* fc1w = (const float*)d_in[23];
    const float* fc1b = (const float*)d_in[24];
    const float* fc2w = (const float*)d_in[25];
    const float* fc2b = (const float*)d_in[26];
    const float* fc3w = (const float*)d_in[27];
    const float* fc3b = (const float*)d_in[28];

    // ---- workspace layout (bytes, 16-aligned) ----
    char* W = (char*)d_ws;
    __bf16* hS    = (__bf16*)(W);                   // NE*128*2   = 15,360,000
    float*  xiA   = (float*)(W + 15360000);         // NN*64*4    =  5,120,000
    float*  xiB   = (float*)(W + 20480000);         // NN*64*4    =  5,120,000
    float*  msg   = (float*)(W + 25600000);         // NE*64*4    = 15,360,000
    float*  xs_sum= (float*)(W + 40960000);         // NS*72*4    =    864,000
    float*  cs    = (float*)(W + 41824000);         // NS*4       =     12,000
    float*  xg_sum= (float*)(W + 41836000);         // NG*72*4    =     36,864
    float*  cg    = (float*)(W + 41872864);         // NG*4       =        512
    __bf16* w2t0  = (__bf16*)(W + 41873376);        // 32*2064*2  =    132,096
    __bf16* w2t1  = (__bf16*)(W + 42005472);        // 64*4128*2  =    528,384
    __bf16* w2t2  = (__bf16*)(W + 42533856);        // 64*8256*2  =  1,056,768
    int*    deg   = (int*)(W + 43590624);           // NN*4       =     80,000
    int*    tmp   = (int*)(W + 43670624);           // NN*4       =     80,000
    int*    rowptr= (int*)(W + 43750624);           // (NN+1)*4   ->    80,016
    int*    eord  = (int*)(W + 43830640);           // NE*4       =    240,000
    int*    srcS  = (int*)(W + 44070640);           // NE*4       =    240,000
    // total 44,310,640 bytes

    // zero: pooling accumulators + sort counters
    hipMemsetAsync(xs_sum, 0, (size_t)(NS * 72 + NS) * 4 + (size_t)(NG * 72 + NG) * 4, stream);
    hipMemsetAsync(deg, 0, 160000, stream);

    // ---- one-time edge sort by dst ----
    k_hist<<<(NE + 255) / 256, 256, 0, stream>>>(dst, deg);
    k_scan<<<1, 1024, 0, stream>>>(deg, rowptr);
    k_scatter<<<(NE + 255) / 256, 256, 0, stream>>>(src, dst, rowptr, tmp, eord, srcS);

    // prep: transposed bf16 W2 (with b2 folded as k==128)
    k_w2t<16, 32><<<(32 * 129 * 16 + 255) / 256, 256, 0, stream>>>(cw2[0], cb2[0], w2t0);
    k_w2t<32, 64><<<(64 * 129 * 32 + 255) / 256, 256, 0, stream>>>(cw2[1], cb2[1], w2t1);
    k_w2t<64, 64><<<(64 * 129 * 64 + 255) / 256, 256, 0, stream>>>(cw2[2], cb2[2], w2t2);

    const int EBX = (NE + 127) / 128;   // 469
    const int HB  = (NE * HIDN + 255) / 256;

    // ---- layer 0: MI=16, MO=32, x (stride 24) -> xiB ----
    k_h<<<HB, 256, 0, stream>>>(eord, ea, cw1[0], cb1[0], hS);
    k_edge2<16, 32, 24><<<dim3(EBX, 1), 128, 0, stream>>>(x, hS, w2t0, srcS, msg);
    k_agg<16, 32, 24><<<(NN * 32 + 255) / 256, 256, 0, stream>>>(msg, rowptr, x, croot[0], cbias[0], xiB);

    // ---- layer 1: MI=32, MO=64, xiB -> xiA ----
    k_h<<<HB, 256, 0, stream>>>(eord, ea, cw1[1], cb1[1], hS);
    k_edge2<32, 64, 32><<<dim3(EBX, 2), 128, 0, stream>>>(xiB, hS, w2t1, srcS, msg);
    k_agg<32, 64, 32><<<(NN * 64 + 255) / 256, 256, 0, stream>>>(msg, rowptr, xiB, croot[1], cbias[1], xiA);

    // ---- layer 2: MI=64, MO=64, xiA -> xiB ----
    k_h<<<HB, 256, 0, stream>>>(eord, ea, cw1[2], cb1[2], hS);
    k_edge2<64, 64, 64><<<dim3(EBX, 2), 128, 0, stream>>>(xiA, hS, w2t2, srcS, msg);
    k_agg<64, 64, 64><<<(NN * 64 + 255) / 256, 256, 0, stream>>>(msg, rowptr, xiA, croot[2], cbias[2], xiB);

    // ---- pooling + MLP ----
    k_pool_s<<<(NN * 72 + 255) / 256, 256, 0, stream>>>(xiB, x, n2s, xs_sum, cs);
    k_pool_g<<<(NS * 72 + 255) / 256, 256, 0, stream>>>(xs_sum, cs, s2g, xg_sum, cg);
    k_fc<<<1, 128, 0, stream>>>(xg_sum, cg, fc1w, fc1b, fc2w, fc2b, fc3w, fc3b, (float*)d_out);
}

// Round 8
// 395.034 us; speedup vs baseline: 2.1031x; 1.0752x over previous
//
#include <hip/hip_runtime.h>
#include <hip/hip_bf16.h>
#include <cmath>

#define NN 20000   // nodes
#define NE 60000   // edges
#define NS 3000    // subgraphs
#define NG 128     // graphs
#define HIDN 128   // hidden dim of edge-attr MLP

typedef float f32x16 __attribute__((ext_vector_type(16)));
typedef __bf16 bf16x8 __attribute__((ext_vector_type(8)));

__device__ __forceinline__ float eluf(float v) { return v > 0.f ? v : expm1f(v); }

template <int CH>
struct alignas((CH * 2 < 16) ? (CH * 2) : 16) HPack { __bf16 v[CH]; };

// async global->LDS, 16B per lane; lds ptr must be wave-uniform (HW writes base + lane*16)
__device__ __forceinline__ void gload_lds16(const void* g, void* l) {
    __builtin_amdgcn_global_load_lds(
        (const __attribute__((address_space(1))) unsigned int*)g,
        (__attribute__((address_space(3))) unsigned int*)l, 16, 0, 0);
}

// ================= one-time edge sort by dst (counting sort) =================
__global__ void k_hist(const int* __restrict__ dst, int* __restrict__ deg) {
    int e = blockIdx.x * 256 + threadIdx.x;
    if (e < NE) atomicAdd(&deg[dst[e]], 1);
}

// single block, 1024 threads: exclusive prefix over NN bins -> rowptr[NN+1]
__global__ void k_scan(const int* __restrict__ deg, int* __restrict__ rowptr) {
    __shared__ int buf[1024];
    const int t = threadIdx.x;
    if (t == 0) rowptr[0] = 0;
    int carry = 0;
    for (int base = 0; base < NN; base += 1024) {
        int v = (base + t < NN) ? deg[base + t] : 0;
        buf[t] = v;
        __syncthreads();
        for (int off = 1; off < 1024; off <<= 1) {
            int add = (t >= off) ? buf[t - off] : 0;
            __syncthreads();
            buf[t] += add;
            __syncthreads();
        }
        if (base + t < NN) rowptr[base + t + 1] = carry + buf[t];
        int total = buf[1023];
        __syncthreads();
        carry += total;
    }
}

__global__ void k_scatter(const int* __restrict__ src, const int* __restrict__ dst,
                          const int* __restrict__ rowptr, int* __restrict__ tmp,
                          int* __restrict__ eord, int* __restrict__ srcS) {
    int e = blockIdx.x * 256 + threadIdx.x;
    if (e >= NE) return;
    int d = dst[e];
    int pos = rowptr[d] + atomicAdd(&tmp[d], 1);
    eord[pos] = e;
    srcS[pos] = src[e];
}

// ---------------- h = relu(ea @ w1 + b1) in SORTED edge order (E x 128, bf16) ----------------
__global__ void k_h(const int* __restrict__ eord, const float* __restrict__ ea,
                    const float* __restrict__ w1, const float* __restrict__ b1,
                    __bf16* __restrict__ hS) {
    int idx = blockIdx.x * 256 + threadIdx.x;
    if (idx >= NE * HIDN) return;
    int jj = idx >> 7, j = idx & 127;
    int e = eord[jj];
    float s = b1[j];
#pragma unroll
    for (int d = 0; d < 5; ++d) s = fmaf(ea[e * 5 + d], w1[d * HIDN + j], s);
    hS[idx] = (__bf16)fmaxf(s, 0.f);
}

// ---------------- w2t[o][kg] = bf16( kg<128*MI ? w2[kg*MO+o] : b2[(kg-128MI)*MO+o] ) ----------------
template <int MI, int MO>
__global__ void k_w2t(const float* __restrict__ w2, const float* __restrict__ b2,
                      __bf16* __restrict__ w2t) {
    constexpr int KP = 129 * MI;
    constexpr int KF = 128 * MI;
    int idx = blockIdx.x * 256 + threadIdx.x;
    if (idx >= MO * KP) return;
    int o = idx / KP, kg = idx % KP;
    float v = (kg < KF) ? w2[(size_t)kg * MO + o] : b2[(kg - KF) * MO + o];
    w2t[idx] = (__bf16)v;
}

// ---------------- MFMA edge kernel: full-MO waves, in-block K-split ----------------
// msg[j,o] = sum_kg G[j,kg]*w2t[o][kg],  G[j, k*MI+i] = hfac(j,k)*xi[srcS[j],i]
// Block = 4 waves: wave (mg,kh) = 64 edges (2 M-tiles) x full MO x k-half [kh*64, kh*64+64).
// B double-buffered per k-half in LDS via global_load_lds. x resident as f32.
// K-halves merged in-block via LDS; single plain store to msg. b2-tail on kh==1.
template <int MI, int MO, int XS>
__global__ __launch_bounds__(256, 2) void k_edge3(
    const float* __restrict__ xi, const __bf16* __restrict__ hS,
    const __bf16* __restrict__ w2t, const int* __restrict__ srcS,
    float* __restrict__ msg) {
    constexpr int PH  = MI / 16;        // K-steps per k value
    constexpr int KP  = 129 * MI;       // w2t row length
    constexpr int NT  = MO / 32;        // N tiles
    constexpr int CH  = 16 / (PH * NT); // k values per chunk (ITEMS = 16)
    constexpr int NCH = 64 / CH;        // chunks per k-half
    static_assert(CH * PH * NT == 16, "ITEMS must be 16");

    __shared__ __align__(16) __bf16 sb[2][2][16 * 512];   // [kh][dbuf][16KB]

    const int lane = threadIdx.x & 63;
    const int w    = threadIdx.x >> 6;
    const int mg   = w & 1;             // edge-group
    const int kh   = w >> 1;            // k-half
    const int lo5  = lane & 31;
    const int hi   = lane >> 5;
    const int e0   = blockIdx.x * 128 + mg * 64;
    const int kb   = kh * 64;

    const int rc0 = min(e0 + lo5, NE - 1);
    const int rc1 = min(e0 + 32 + lo5, NE - 1);
    const int s0 = srcS[rc0];
    const int s1 = srcS[rc1];

    // x fragments resident as f32 (no unpack in hot loop)
    float xr0[PH][8], xr1[PH][8];
    {
        const float* xb0 = xi + (size_t)s0 * XS + hi * 8;
        const float* xb1 = xi + (size_t)s1 * XS + hi * 8;
#pragma unroll
        for (int p = 0; p < PH; ++p) {
            float4 a = *reinterpret_cast<const float4*>(xb0 + p * 16);
            float4 b = *reinterpret_cast<const float4*>(xb0 + p * 16 + 4);
            xr0[p][0] = a.x; xr0[p][1] = a.y; xr0[p][2] = a.z; xr0[p][3] = a.w;
            xr0[p][4] = b.x; xr0[p][5] = b.y; xr0[p][6] = b.z; xr0[p][7] = b.w;
            float4 c = *reinterpret_cast<const float4*>(xb1 + p * 16);
            float4 d = *reinterpret_cast<const float4*>(xb1 + p * 16 + 4);
            xr1[p][0] = c.x; xr1[p][1] = c.y; xr1[p][2] = c.z; xr1[p][3] = c.w;
            xr1[p][4] = d.x; xr1[p][5] = d.y; xr1[p][6] = d.z; xr1[p][7] = d.w;
        }
    }

    f32x16 acc[2][NT];
#pragma unroll
    for (int m = 0; m < 2; ++m)
#pragma unroll
        for (int n = 0; n < NT; ++n)
#pragma unroll
            for (int i = 0; i < 16; ++i) acc[m][n][i] = 0.f;

    const __bf16* h0 = hS + (size_t)rc0 * HIDN + kb;
    const __bf16* h1 = hS + (size_t)rc1 * HIDN + kb;

    // stage one 16KB chunk for this k-half; the 2 waves of a k-half split the 16 items
    auto stage = [&](int buf, int kc) {
#pragma unroll
        for (int jj = 0; jj < 8; ++jj) {
            const int j  = mg + jj * 2;
            const int n  = j % NT;
            const int kp = j / NT;
            const int p  = kp % PH;
            const int kk = kp / PH;
            gload_lds16(w2t + (size_t)(n * 32 + lo5) * KP
                            + (size_t)(kb + kc + kk) * MI + p * 16 + hi * 8,
                        &sb[kh][buf][j * 512]);
        }
    };

    stage(0, 0);
    HPack<CH> hc0 = *reinterpret_cast<const HPack<CH>*>(h0);
    HPack<CH> hc1 = *reinterpret_cast<const HPack<CH>*>(h1);

    for (int c = 0; c < NCH; ++c) {
        __syncthreads();                    // drains chunk-c staging for all waves
        if (c + 1 < NCH) stage((c + 1) & 1, (c + 1) * CH);
        HPack<CH> hn0 = hc0, hn1 = hc1;
        if (c + 1 < NCH) {
            hn0 = *reinterpret_cast<const HPack<CH>*>(h0 + (c + 1) * CH);
            hn1 = *reinterpret_cast<const HPack<CH>*>(h1 + (c + 1) * CH);
        }
        const __bf16* sbc = &sb[kh][c & 1][0];
#pragma unroll
        for (int p = 0; p < PH; ++p) {
#pragma unroll
            for (int kk = 0; kk < CH; ++kk) {
                const float hv0 = (float)hc0.v[kk];
                const float hv1 = (float)hc1.v[kk];
                bf16x8 af0, af1;
#pragma unroll
                for (int j = 0; j < 8; ++j) {
                    af0[j] = (__bf16)(hv0 * xr0[p][j]);
                    af1[j] = (__bf16)(hv1 * xr1[p][j]);
                }
#pragma unroll
                for (int n = 0; n < NT; ++n) {
                    const bf16x8 bv = *reinterpret_cast<const bf16x8*>(
                        &sbc[((kk * PH + p) * NT + n) * 512 + lane * 8]);
                    acc[0][n] = __builtin_amdgcn_mfma_f32_32x32x16_bf16(af0, bv, acc[0][n], 0, 0, 0);
                    acc[1][n] = __builtin_amdgcn_mfma_f32_32x32x16_bf16(af1, bv, acc[1][n], 0, 0, 0);
                }
            }
        }
        hc0 = hn0; hc1 = hn1;
    }

    // k == 128 tail (folded b2 term, hfac = 1) — kh==1 only, direct global B
    if (kh == 1) {
#pragma unroll
        for (int p = 0; p < PH; ++p) {
            bf16x8 af0, af1;
#pragma unroll
            for (int j = 0; j < 8; ++j) {
                af0[j] = (__bf16)xr0[p][j];
                af1[j] = (__bf16)xr1[p][j];
            }
#pragma unroll
            for (int n = 0; n < NT; ++n) {
                const bf16x8 bv = *reinterpret_cast<const bf16x8*>(
                    w2t + (size_t)(n * 32 + lo5) * KP + (size_t)128 * MI + p * 16 + hi * 8);
                acc[0][n] = __builtin_amdgcn_mfma_f32_32x32x16_bf16(af0, bv, acc[0][n], 0, 0, 0);
                acc[1][n] = __builtin_amdgcn_mfma_f32_32x32x16_bf16(af1, bv, acc[1][n], 0, 0, 0);
            }
        }
    }

    // ---- merge k-halves via LDS (reuse sb), then single store by kh==0 waves ----
    __syncthreads();                        // all compute done, sb free
    float* red = reinterpret_cast<float*>(&sb[0][0][0]);
    if (kh == 1) {
#pragma unroll
        for (int m = 0; m < 2; ++m)
#pragma unroll
            for (int n = 0; n < NT; ++n) {
                float* dst = red + (size_t)(((mg * 2 + m) * NT + n) * 64 + lane) * 16;
#pragma unroll
                for (int q = 0; q < 4; ++q) {
                    float4 v = make_float4(acc[m][n][4 * q], acc[m][n][4 * q + 1],
                                           acc[m][n][4 * q + 2], acc[m][n][4 * q + 3]);
                    *reinterpret_cast<float4*>(dst + q * 4) = v;
                }
            }
    }
    __syncthreads();
    if (kh == 0) {
#pragma unroll
        for (int m = 0; m < 2; ++m)
#pragma unroll
            for (int n = 0; n < NT; ++n) {
                const float* s = red + (size_t)(((mg * 2 + m) * NT + n) * 64 + lane) * 16;
#pragma unroll
                for (int i = 0; i < 16; ++i) acc[m][n][i] += s[i];
            }
        // store: C layout col = lane&31, row = (reg&3) + 8*(reg>>2) + 4*(lane>>5)
#pragma unroll
        for (int m = 0; m < 2; ++m)
#pragma unroll
            for (int q = 0; q < 4; ++q)
#pragma unroll
                for (int a = 0; a < 4; ++a) {
                    const int e = e0 + m * 32 + 4 * hi + 8 * q + a;
                    if (e < NE) {
#pragma unroll
                        for (int n = 0; n < NT; ++n)
                            msg[(size_t)e * MO + n * 32 + lo5] = acc[m][n][4 * q + a];
                    }
                }
    }
}

// ---------------- agg: out[n,o] = elu( bias[o] + xi@root + sum_{j in CSR[n]} msg[j,o] ) ----------------
template <int MI, int MO, int XS>
__global__ void k_agg(const float* __restrict__ msg, const int* __restrict__ rowptr,
                      const float* __restrict__ xi, const float* __restrict__ root,
                      const float* __restrict__ bias, float* __restrict__ out) {
    int idx = blockIdx.x * 256 + threadIdx.x;
    if (idx >= NN * MO) return;
    int n = idx / MO, o = idx % MO;
    float s = bias[o];
#pragma unroll
    for (int i = 0; i < MI; ++i) s = fmaf(xi[(size_t)n * XS + i], root[i * MO + o], s);
    const int j0 = rowptr[n], j1 = rowptr[n + 1];
    for (int j = j0; j < j1; ++j) s += msg[(size_t)j * MO + o];
    out[idx] = eluf(s);
}

// ---------------- pool nodes -> subgraphs (sum + count) ----------------
__global__ void k_pool_s(const float* __restrict__ xi, const float* __restrict__ x,
                         const int* __restrict__ n2s, float* __restrict__ xs_sum,
                         float* __restrict__ cs) {
    int idx = blockIdx.x * 256 + threadIdx.x;
    if (idx >= NN * 72) return;
    int n = idx / 72, j = idx % 72;
    float v = (j < 64) ? xi[n * 64 + j] : x[n * 24 + 16 + (j - 64)];
    int s = n2s[n];
    atomicAdd(&xs_sum[s * 72 + j], v);
    if (j == 0) atomicAdd(&cs[s], 1.f);
}

// ---------------- pool subgraphs -> graphs (mean of means) ----------------
__global__ void k_pool_g(const float* __restrict__ xs_sum, const float* __restrict__ cs,
                         const int* __restrict__ s2g, float* __restrict__ xg_sum,
                         float* __restrict__ cg) {
    int idx = blockIdx.x * 256 + threadIdx.x;
    if (idx >= NS * 72) return;
    int s = idx / 72, j = idx % 72;
    float v = xs_sum[s * 72 + j] / fmaxf(cs[s], 1.f);
    int g = s2g[s];
    atomicAdd(&xg_sum[g * 72 + j], v);
    if (j == 0) atomicAdd(&cg[g], 1.f);
}

// ---------------- final MLP: 72 -> 36 -> 18 -> 1 ----------------
__global__ void k_fc(const float* __restrict__ xg_sum, const float* __restrict__ cg,
                     const float* __restrict__ w1, const float* __restrict__ b1,
                     const float* __restrict__ w2, const float* __restrict__ b2,
                     const float* __restrict__ w3, const float* __restrict__ b3,
                     float* __restrict__ out) {
    int g = threadIdx.x;
    if (g >= NG) return;
    float inv = 1.f / fmaxf(cg[g], 1.f);
    float v[72];
#pragma unroll
    for (int j = 0; j < 72; ++j) v[j] = xg_sum[g * 72 + j] * inv;
    float h1[36];
#pragma unroll
    for (int o = 0; o < 36; ++o) {
        float s = b1[o];
#pragma unroll
        for (int i = 0; i < 72; ++i) s = fmaf(v[i], w1[i * 36 + o], s);
        h1[o] = eluf(s);
    }
    float h2[18];
#pragma unroll
    for (int o = 0; o < 18; ++o) {
        float s = b2[o];
#pragma unroll
        for (int i = 0; i < 36; ++i) s = fmaf(h1[i], w2[i * 18 + o], s);
        h2[o] = eluf(s);
    }
    float s = b3[0];
#pragma unroll
    for (int i = 0; i < 18; ++i) s = fmaf(h2[i], w3[i], s);
    out[g] = s;
}

// ---------------- launcher ----------------
extern "C" void kernel_launch(void* const* d_in, const int* in_sizes, int n_in,
                              void* d_out, int out_size, void* d_ws, size_t ws_size,
                              hipStream_t stream) {
    const float* x   = (const float*)d_in[0];
    const int*   ei  = (const int*)d_in[1];
    const float* ea  = (const float*)d_in[2];
    const int*   n2s = (const int*)d_in[3];
    const int*   s2g = (const int*)d_in[4];
    const int* src = ei;
    const int* dst = ei + NE;

    const float* cw1[3]   = {(const float*)d_in[5],  (const float*)d_in[11], (const float*)d_in[17]};
    const float* cb1[3]   = {(const float*)d_in[6],  (const float*)d_in[12], (const float*)d_in[18]};
    const float* cw2[3]   = {(const float*)d_in[7],  (const float*)d_in[13], (const float*)d_in[19]};
    const float* cb2[3]   = {(const float*)d_in[8],  (const float*)d_in[14], (const float*)d_in[20]};
    const float* croot[3] = {(const float*)d_in[9],  (const float*)d_in[15], (const float*)d_in[21]};
    const float* cbias[3] = {(const float*)d_in[10], (const float*)d_in[16], (const float*)d_in[22]};
    const float* fc1w = (const float*)d_in[23];
    const float* fc1b = (const float*)d_in[24];
    const float* fc2w = (const float*)d_in[25];
    const float* fc2b = (const float*)d_in[26];
    const float* fc3w = (const float*)d_in[27];
    const float* fc3b = (const float*)d_in[28];

    // ---- workspace layout (bytes, 16-aligned) ----
    char* W = (char*)d_ws;
    __bf16* hS    = (__bf16*)(W);                   // NE*128*2   = 15,360,000
    float*  xiA   = (float*)(W + 15360000);         // NN*64*4    =  5,120,000
    float*  xiB   = (float*)(W + 20480000);         // NN*64*4    =  5,120,000
    float*  msg   = (float*)(W + 25600000);         // NE*64*4    = 15,360,000
    float*  xs_sum= (float*)(W + 40960000);         // NS*72*4    =    864,000
    float*  cs    = (float*)(W + 41824000);         // NS*4       =     12,000
    float*  xg_sum= (float*)(W + 41836000);         // NG*72*4    =     36,864
    float*  cg    = (float*)(W + 41872864);         // NG*4       =        512
    __bf16* w2t0  = (__bf16*)(W + 41873376);        // 32*2064*2  =    132,096
    __bf16* w2t1  = (__bf16*)(W + 42005472);        // 64*4128*2  =    528,384
    __bf16* w2t2  = (__bf16*)(W + 42533856);        // 64*8256*2  =  1,056,768
    int*    deg   = (int*)(W + 43590624);           // NN*4       =     80,000
    int*    tmp   = (int*)(W + 43670624);           // NN*4       =     80,000
    int*    rowptr= (int*)(W + 43750624);           // (NN+1)*4   ->    80,016
    int*    eord  = (int*)(W + 43830640);           // NE*4       =    240,000
    int*    srcS  = (int*)(W + 44070640);           // NE*4       =    240,000
    // total 44,310,640 bytes

    // zero: pooling accumulators + sort counters
    hipMemsetAsync(xs_sum, 0, (size_t)(NS * 72 + NS) * 4 + (size_t)(NG * 72 + NG) * 4, stream);
    hipMemsetAsync(deg, 0, 160000, stream);

    // ---- one-time edge sort by dst ----
    k_hist<<<(NE + 255) / 256, 256, 0, stream>>>(dst, deg);
    k_scan<<<1, 1024, 0, stream>>>(deg, rowptr);
    k_scatter<<<(NE + 255) / 256, 256, 0, stream>>>(src, dst, rowptr, tmp, eord, srcS);

    // prep: transposed bf16 W2 (with b2 folded as k==128)
    k_w2t<16, 32><<<(32 * 129 * 16 + 255) / 256, 256, 0, stream>>>(cw2[0], cb2[0], w2t0);
    k_w2t<32, 64><<<(64 * 129 * 32 + 255) / 256, 256, 0, stream>>>(cw2[1], cb2[1], w2t1);
    k_w2t<64, 64><<<(64 * 129 * 64 + 255) / 256, 256, 0, stream>>>(cw2[2], cb2[2], w2t2);

    const int EB3 = (NE + 127) / 128;   // 469 blocks of 4 waves
    const int HB  = (NE * HIDN + 255) / 256;

    // ---- layer 0: MI=16, MO=32, x (stride 24) -> xiB ----
    k_h<<<HB, 256, 0, stream>>>(eord, ea, cw1[0], cb1[0], hS);
    k_edge3<16, 32, 24><<<EB3, 256, 0, stream>>>(x, hS, w2t0, srcS, msg);
    k_agg<16, 32, 24><<<(NN * 32 + 255) / 256, 256, 0, stream>>>(msg, rowptr, x, croot[0], cbias[0], xiB);

    // ---- layer 1: MI=32, MO=64, xiB -> xiA ----
    k_h<<<HB, 256, 0, stream>>>(eord, ea, cw1[1], cb1[1], hS);
    k_edge3<32, 64, 32><<<EB3, 256, 0, stream>>>(xiB, hS, w2t1, srcS, msg);
    k_agg<32, 64, 32><<<(NN * 64 + 255) / 256, 256, 0, stream>>>(msg, rowptr, xiB, croot[1], cbias[1], xiA);

    // ---- layer 2: MI=64, MO=64, xiA -> xiB ----
    k_h<<<HB, 256, 0, stream>>>(eord, ea, cw1[2], cb1[2], hS);
    k_edge3<64, 64, 64><<<EB3, 256, 0, stream>>>(xiA, hS, w2t2, srcS, msg);
    k_agg<64, 64, 64><<<(NN * 64 + 255) / 256, 256, 0, stream>>>(msg, rowptr, xiA, croot[2], cbias[2], xiB);

    // ---- pooling + MLP ----
    k_pool_s<<<(NN * 72 + 255) / 256, 256, 0, stream>>>(xiB, x, n2s, xs_sum, cs);
    k_pool_g<<<(NS * 72 + 255) / 256, 256, 0, stream>>>(xs_sum, cs, s2g, xg_sum, cg);
    k_fc<<<1, 128, 0, stream>>>(xg_sum, cg, fc1w, fc1b, fc2w, fc2b, fc3w, fc3b, (float*)d_out);
}